// Round 6
// baseline (3844.024 us; speedup 1.0000x reference)
//
#include <hip/hip_runtime.h>
#include <hip/hip_bf16.h>
#include <cstdint>
#include <cstddef>

// Problem constants
#define BB 4
#define SS 256
#define ID 512
#define HD 1024
#define MD 256
#define NKEY 65536
#define OD 512
#define ROWS 1024          // B*S
#define NS 16              // key-range splits for sim/topk
#define KEYS_PER_NS (NKEY / NS)
#define NWG_LSTM 64
#define NTH_LSTM 1024

// ---------------------------------------------------------------------------
// Coherent (fence-free, cross-XCD) access helpers: sc0 sc1 bypass the
// non-coherent L1/L2 and hit the memory-side coherent point directly.
// ---------------------------------------------------------------------------
__device__ inline void coh_store_pair(unsigned* p, float h, unsigned tag) {
    uint2 v; v.x = __float_as_uint(h); v.y = tag;   // 8B single-instruction store:
    asm volatile("global_store_dwordx2 %0, %1, off sc0 sc1"  // h+tag visible atomically
                 :: "v"(p), "v"(v) : "memory");
}

// ---------------------------------------------------------------------------
// Generic SGEMM: C[M,N] = A[M,K] * Bm[N,K]^T (+bias(+bias2)) or C += ...
// 64x64 tile, 256 threads, 4x4 micro-tile. Grid: (N/64, M/64).
// ---------------------------------------------------------------------------
__global__ __launch_bounds__(256) void sgemm_nt(
    const float* __restrict__ A, int lda,
    const float* __restrict__ Bm, int ldb,
    float* __restrict__ C, int ldc, int K,
    const float* __restrict__ bias, const float* __restrict__ bias2,
    int accum)
{
    __shared__ float As[64][17];
    __shared__ float Bs[64][17];
    const int t = threadIdx.x;
    const int tx = t & 15, ty = t >> 4;
    const int bm = blockIdx.y << 6, bn = blockIdx.x << 6;
    const int lrow = t >> 2, lk4 = (t & 3) << 2;
    float acc[4][4] = {};

    for (int kb = 0; kb < K; kb += 16) {
        const float4 av = *(const float4*)&A[(size_t)(bm + lrow) * lda + kb + lk4];
        const float4 bv = *(const float4*)&Bm[(size_t)(bn + lrow) * ldb + kb + lk4];
        __syncthreads();
        As[lrow][lk4 + 0] = av.x; As[lrow][lk4 + 1] = av.y;
        As[lrow][lk4 + 2] = av.z; As[lrow][lk4 + 3] = av.w;
        Bs[lrow][lk4 + 0] = bv.x; Bs[lrow][lk4 + 1] = bv.y;
        Bs[lrow][lk4 + 2] = bv.z; Bs[lrow][lk4 + 3] = bv.w;
        __syncthreads();
#pragma unroll
        for (int k = 0; k < 16; ++k) {
            const float a0 = As[4 * ty + 0][k], a1 = As[4 * ty + 1][k];
            const float a2 = As[4 * ty + 2][k], a3 = As[4 * ty + 3][k];
            const float b0 = Bs[4 * tx + 0][k], b1 = Bs[4 * tx + 1][k];
            const float b2 = Bs[4 * tx + 2][k], b3 = Bs[4 * tx + 3][k];
            acc[0][0] += a0 * b0; acc[0][1] += a0 * b1; acc[0][2] += a0 * b2; acc[0][3] += a0 * b3;
            acc[1][0] += a1 * b0; acc[1][1] += a1 * b1; acc[1][2] += a1 * b2; acc[1][3] += a1 * b3;
            acc[2][0] += a2 * b0; acc[2][1] += a2 * b1; acc[2][2] += a2 * b2; acc[2][3] += a2 * b3;
            acc[3][0] += a3 * b0; acc[3][1] += a3 * b1; acc[3][2] += a3 * b2; acc[3][3] += a3 * b3;
        }
    }

#pragma unroll
    for (int i = 0; i < 4; ++i) {
        const int row = bm + 4 * ty + i;
        const int col = bn + 4 * tx;
        float4* cp = (float4*)&C[(size_t)row * ldc + col];
        float4 r;
        if (accum) {
            const float4 old = *cp;
            r.x = old.x + acc[i][0]; r.y = old.y + acc[i][1];
            r.z = old.z + acc[i][2]; r.w = old.w + acc[i][3];
        } else {
            float bx = bias[col + 0], by = bias[col + 1], bz = bias[col + 2], bw = bias[col + 3];
            if (bias2) { bx += bias2[col + 0]; by += bias2[col + 1]; bz += bias2[col + 2]; bw += bias2[col + 3]; }
            r.x = acc[i][0] + bx; r.y = acc[i][1] + by;
            r.z = acc[i][2] + bz; r.w = acc[i][3] + bw;
        }
        *cp = r;
    }
}

// ---------------------------------------------------------------------------
// Row L2-normalization helper (256-column rows).
// ---------------------------------------------------------------------------
__global__ void rownorm(const float* __restrict__ X, const float* __restrict__ imp,
                        float* __restrict__ scale_out, float* __restrict__ Xn, int nrows)
{
    const int row = blockIdx.x * 4 + (threadIdx.x >> 6);
    const int lane = threadIdx.x & 63;
    if (row >= nrows) return;
    float4 v = *(const float4*)&X[(size_t)row * 256 + (lane << 2)];
    float ss = v.x * v.x + v.y * v.y + v.z * v.z + v.w * v.w;
#pragma unroll
    for (int o = 1; o < 64; o <<= 1) ss += __shfl_xor(ss, o);
    float sc = 1.f / fmaxf(sqrtf(ss), 1e-12f);
    if (imp) sc *= imp[row];
    if (scale_out && lane == 0) scale_out[row] = sc;
    if (Xn) {
        v.x *= sc; v.y *= sc; v.z *= sc; v.w *= sc;
        *(float4*)&Xn[(size_t)row * 256 + (lane << 2)] = v;
    }
}

// ---------------------------------------------------------------------------
// Persistent LSTM: 64 wgs x 1024 threads (16 waves). Wave w of wg g owns
// hidden unit (16g+w); its 4 W_hh gate rows live in registers (64 f/lane).
// Cross-wg h exchange via tagged records, layout [unit][b]:
//   rec[slot][(unit*4+b)] = {f32 h, u32 step_tag}  (8B coherent dwordx2 store)
// Thread t polls unit t's 4 contiguous records (32B, 2 dwordx4, coalesced);
// the successful poll IS the h load. De-interleave to LDS is stride-1
// (conflict-free). No flags, no grid barrier, no fences.
// ---------------------------------------------------------------------------
__device__ inline float sigm_f(float x) { return 1.f / (1.f + __expf(-x)); }
__device__ inline float tanh_f(float x) { return 1.f - 2.f / (__expf(2.f * x) + 1.f); }

__global__ __launch_bounds__(1024) void lstm_kernel(
    const float* __restrict__ xp, const float* __restrict__ W_hh,
    unsigned* __restrict__ rec, float* __restrict__ h_all)
{
    __shared__ float h_lds[4 * 1024];
    const int t = threadIdx.x;                    // 0..1023
    const int wave = t >> 6, lane = t & 63;
    const int gt = lane >> 4, ksub = lane & 15;   // gate 0..3 (i,f,g,o), k-sub 0..15
    const int unit = (blockIdx.x << 4) + wave;
    const int wrow = (gt << 10) + unit;           // W_hh row

    float4 w4[16];
#pragma unroll
    for (int j = 0; j < 16; ++j)
        w4[j] = *(const float4*)&W_hh[(size_t)wrow * 1024 + (ksub << 2) + (j << 6)];

    float c[4] = {0.f, 0.f, 0.f, 0.f};           // cell state, replicated per-lane

    // prefetch xp for step 0 (constant data, plain cached loads)
    float xpv[4];
#pragma unroll
    for (int b = 0; b < 4; ++b)
        xpv[b] = xp[(size_t)((b << 8) + 0) * 4096 + wrow];

    for (int s = 0; s < 256; ++s) {
        // ---- poll + load unit t's 4 records (32B, coalesced) ----
        const unsigned* base = rec + ((size_t)(s & 1) << 13) + (t << 3);
        uint4 r0, r1;
        const unsigned st = (unsigned)s;
        while (1) {
            asm volatile(
                "global_load_dwordx4 %0, %2, off sc0 sc1\n\t"
                "global_load_dwordx4 %1, %2, off offset:16 sc0 sc1\n\t"
                "s_waitcnt vmcnt(0)"
                : "=&v"(r0), "=&v"(r1)
                : "v"(base) : "memory");
            const unsigned m = (r0.y ^ st) | (r0.w ^ st) | (r1.y ^ st) | (r1.w ^ st);
            if (m == 0u) break;
            __builtin_amdgcn_s_sleep(1);
        }
        // stride-1 de-interleave -> conflict-free LDS writes
        h_lds[t]        = __uint_as_float(r0.x);
        h_lds[1024 + t] = __uint_as_float(r0.z);
        h_lds[2048 + t] = __uint_as_float(r1.x);
        h_lds[3072 + t] = __uint_as_float(r1.z);
        __syncthreads();

        float sum[4];
#pragma unroll
        for (int b = 0; b < 4; ++b) {
            const float* hb = &h_lds[b << 10];
            float ax = 0.f, ay = 0.f, az = 0.f, aw = 0.f;
#pragma unroll
            for (int j = 0; j < 16; ++j) {
                const float4 hv = *(const float4*)&hb[(ksub << 2) + (j << 6)];
                ax += w4[j].x * hv.x; ay += w4[j].y * hv.y;
                az += w4[j].z * hv.z; aw += w4[j].w * hv.w;
            }
            float sm = (ax + ay) + (az + aw);
            sm += __shfl_xor(sm, 1); sm += __shfl_xor(sm, 2);
            sm += __shfl_xor(sm, 4); sm += __shfl_xor(sm, 8);
            sum[b] = sm + xpv[b];                // gate preact, replicated over ksub lanes
        }

#pragma unroll
        for (int b = 0; b < 4; ++b) {
            const float vi = __shfl(sum[b], ksub);
            const float vf = __shfl(sum[b], ksub + 16);
            const float vg = __shfl(sum[b], ksub + 32);
            const float vo = __shfl(sum[b], ksub + 48);
            const float iv = sigm_f(vi), fv = sigm_f(vf);
            const float gv = tanh_f(vg), ov = sigm_f(vo);
            c[b] = fv * c[b] + iv * gv;
            const float hv = ov * tanh_f(c[b]);
            if (lane == b) {
                coh_store_pair(rec + (((size_t)((s + 1) & 1)) << 13) + (((unit << 2) + b) << 1),
                               hv, (unsigned)(s + 1));
                h_all[(size_t)((b << 8) + s) * 1024 + unit] = hv;   // archive, plain store
            }
        }

        if (s == 255) break;
        // prefetch xp for step s+1 (off the critical path, cached)
#pragma unroll
        for (int b = 0; b < 4; ++b)
            xpv[b] = xp[(size_t)((b << 8) + s + 1) * 4096 + wrow];
        // NOTE: no barrier needed. A thread's next-step poll can only succeed
        // after ALL waves stored step s+1 records, which data-depends on
        // their step-s LDS reads -> safe to overwrite h_lds after poll.
    }
}

// ---------------------------------------------------------------------------
// Fused cosine-sim GEMM + running top-3.
// Grid: (NS, 16). Block 256 (16tx x 16ty), micro 4q x 4k from k-major LDS.
// ---------------------------------------------------------------------------
__global__ __launch_bounds__(256) void sim_topk(
    const float* __restrict__ qn, const float* __restrict__ keys,
    const float* __restrict__ rnk, float* __restrict__ part_v, int* __restrict__ part_i)
{
    __shared__ float Qs[256 * 64];   // k-major: Qs[k*64 + q]
    __shared__ float Ks[256 * 64];   // k-major: Ks[k*64 + key]
    const int t = threadIdx.x;
    const int tx = t & 15, ty = t >> 4;
    const int ns = blockIdx.x, qb = blockIdx.y;
    const int q0 = qb << 6;
    const int rl = t >> 2, c0 = t & 3;

#pragma unroll
    for (int i = 0; i < 16; ++i) {
        const int ch = c0 + (i << 2);
        const float4 v = *(const float4*)&qn[(size_t)(q0 + rl) * 256 + (ch << 2)];
        const int k = ch << 2;
        Qs[(k + 0) * 64 + rl] = v.x; Qs[(k + 1) * 64 + rl] = v.y;
        Qs[(k + 2) * 64 + rl] = v.z; Qs[(k + 3) * 64 + rl] = v.w;
    }

    float rv[4][3]; int ri[4][3];
#pragma unroll
    for (int i = 0; i < 4; ++i) {
        rv[i][0] = rv[i][1] = rv[i][2] = -3e38f;
        ri[i][0] = ri[i][1] = ri[i][2] = 0;
    }

    for (int tile = 0; tile < KEYS_PER_NS / 64; ++tile) {
        const int key0 = ns * KEYS_PER_NS + (tile << 6);
        const float sc = rnk[key0 + rl];
        float4 kreg[16];
#pragma unroll
        for (int i = 0; i < 16; ++i)
            kreg[i] = *(const float4*)&keys[(size_t)(key0 + rl) * 256 + ((c0 + (i << 2)) << 2)];
        __syncthreads();
#pragma unroll
        for (int i = 0; i < 16; ++i) {
            const int k = (c0 + (i << 2)) << 2;
            Ks[(k + 0) * 64 + rl] = kreg[i].x * sc;
            Ks[(k + 1) * 64 + rl] = kreg[i].y * sc;
            Ks[(k + 2) * 64 + rl] = kreg[i].z * sc;
            Ks[(k + 3) * 64 + rl] = kreg[i].w * sc;
        }
        __syncthreads();

        float acc[4][4] = {};
#pragma unroll 4
        for (int k = 0; k < 256; ++k) {
            const float4 a = *(const float4*)&Qs[k * 64 + (ty << 2)];
            const float4 b = *(const float4*)&Ks[k * 64 + (tx << 2)];
            acc[0][0] += a.x * b.x; acc[0][1] += a.x * b.y; acc[0][2] += a.x * b.z; acc[0][3] += a.x * b.w;
            acc[1][0] += a.y * b.x; acc[1][1] += a.y * b.y; acc[1][2] += a.y * b.z; acc[1][3] += a.y * b.w;
            acc[2][0] += a.z * b.x; acc[2][1] += a.z * b.y; acc[2][2] += a.z * b.z; acc[2][3] += a.z * b.w;
            acc[3][0] += a.w * b.x; acc[3][1] += a.w * b.y; acc[3][2] += a.w * b.z; acc[3][3] += a.w * b.w;
        }

#pragma unroll
        for (int i = 0; i < 4; ++i) {
#pragma unroll
            for (int j = 0; j < 4; ++j) {
                const float v = acc[i][j];
                const int gk = key0 + (tx << 2) + j;
                if (v > rv[i][2]) {
                    if (v > rv[i][0]) {
                        rv[i][2] = rv[i][1]; ri[i][2] = ri[i][1];
                        rv[i][1] = rv[i][0]; ri[i][1] = ri[i][0];
                        rv[i][0] = v; ri[i][0] = gk;
                    } else if (v > rv[i][1]) {
                        rv[i][2] = rv[i][1]; ri[i][2] = ri[i][1];
                        rv[i][1] = v; ri[i][1] = gk;
                    } else {
                        rv[i][2] = v; ri[i][2] = gk;
                    }
                }
            }
        }
    }

    __syncthreads();
    float* cv = Qs;               // reuse LDS: [64 q][16 tx][3]
    int* ci = (int*)Ks;
#pragma unroll
    for (int i = 0; i < 4; ++i)
#pragma unroll
        for (int r = 0; r < 3; ++r) {
            cv[(4 * ty + i) * 48 + tx * 3 + r] = rv[i][r];
            ci[(4 * ty + i) * 48 + tx * 3 + r] = ri[i][r];
        }
    __syncthreads();
    if (t < 64) {
        float bv[3] = {-3e38f, -3e38f, -3e38f};
        int bi[3] = {0x7fffffff, 0x7fffffff, 0x7fffffff};
        for (int cc = 0; cc < 48; ++cc) {
            const float v = cv[t * 48 + cc];
            const int id = ci[t * 48 + cc];
            if (v > bv[0] || (v == bv[0] && id < bi[0])) {
                bv[2] = bv[1]; bi[2] = bi[1]; bv[1] = bv[0]; bi[1] = bi[0]; bv[0] = v; bi[0] = id;
            } else if (v > bv[1] || (v == bv[1] && id < bi[1])) {
                bv[2] = bv[1]; bi[2] = bi[1]; bv[1] = v; bi[1] = id;
            } else if (v > bv[2] || (v == bv[2] && id < bi[2])) {
                bv[2] = v; bi[2] = id;
            }
        }
        const size_t base = (size_t)(q0 + t) * (NS * 3) + ns * 3;
        part_v[base + 0] = bv[0]; part_v[base + 1] = bv[1]; part_v[base + 2] = bv[2];
        part_i[base + 0] = bi[0]; part_i[base + 1] = bi[1]; part_i[base + 2] = bi[2];
    }
}

// ---------------------------------------------------------------------------
__global__ void topk_combine(const float* __restrict__ part_v, const int* __restrict__ part_i,
                             int* __restrict__ top_i)
{
    const int q = blockIdx.x * 256 + threadIdx.x;
    if (q >= ROWS) return;
    float bv[3] = {-3e38f, -3e38f, -3e38f};
    int bi[3] = {0x7fffffff, 0x7fffffff, 0x7fffffff};
    for (int cc = 0; cc < NS * 3; ++cc) {
        const float v = part_v[(size_t)q * (NS * 3) + cc];
        const int id = part_i[(size_t)q * (NS * 3) + cc];
        if (v > bv[0] || (v == bv[0] && id < bi[0])) {
            bv[2] = bv[1]; bi[2] = bi[1]; bv[1] = bv[0]; bi[1] = bi[0]; bv[0] = v; bi[0] = id;
        } else if (v > bv[1] || (v == bv[1] && id < bi[1])) {
            bv[2] = bv[1]; bi[2] = bi[1]; bv[1] = v; bi[1] = id;
        } else if (v > bv[2] || (v == bv[2] && id < bi[2])) {
            bv[2] = v; bi[2] = id;
        }
    }
    top_i[q * 3 + 0] = bi[0]; top_i[q * 3 + 1] = bi[1]; top_i[q * 3 + 2] = bi[2];
}

// ---------------------------------------------------------------------------
__global__ void mem_gather(const int* __restrict__ top_i, const float* __restrict__ values,
                           const float* __restrict__ Wa, const float* __restrict__ ba,
                           float* __restrict__ mem_raw)
{
    const int q = blockIdx.x;
    const int lane = threadIdx.x;   // 0..63
    const float4 wa = *(const float4*)&Wa[lane << 2];
    float4 vr[3];
    float lg[3];
#pragma unroll
    for (int r = 0; r < 3; ++r) {
        const int n = top_i[q * 3 + r];
        const float4 v = *(const float4*)&values[(size_t)n * 256 + (lane << 2)];
        vr[r] = v;
        float d = v.x * wa.x + v.y * wa.y + v.z * wa.z + v.w * wa.w;
#pragma unroll
        for (int o = 1; o < 64; o <<= 1) d += __shfl_xor(d, o);
        lg[r] = d + ba[0];
    }
    const float mx = fmaxf(lg[0], fmaxf(lg[1], lg[2]));
    float e0 = __expf(lg[0] - mx), e1 = __expf(lg[1] - mx), e2 = __expf(lg[2] - mx);
    const float inv = 1.f / (e0 + e1 + e2);
    e0 *= inv; e1 *= inv; e2 *= inv;
    float4 m;
    m.x = e0 * vr[0].x + e1 * vr[1].x + e2 * vr[2].x;
    m.y = e0 * vr[0].y + e1 * vr[1].y + e2 * vr[2].y;
    m.z = e0 * vr[0].z + e1 * vr[1].z + e2 * vr[2].z;
    m.w = e0 * vr[0].w + e1 * vr[1].w + e2 * vr[2].w;
    *(float4*)&mem_raw[(size_t)q * 256 + (lane << 2)] = m;
}

// ---------------------------------------------------------------------------
extern "C" void kernel_launch(void* const* d_in, const int* in_sizes, int n_in,
                              void* d_out, int out_size, void* d_ws, size_t ws_size,
                              hipStream_t stream)
{
    (void)in_sizes; (void)n_in; (void)out_size; (void)ws_size;
    const float* x     = (const float*)d_in[0];
    const float* keys  = (const float*)d_in[1];
    const float* values= (const float*)d_in[2];
    const float* imp   = (const float*)d_in[3];
    const float* W_ih  = (const float*)d_in[4];
    const float* W_hh  = (const float*)d_in[5];
    const float* b_ih  = (const float*)d_in[6];
    const float* b_hh  = (const float*)d_in[7];
    const float* Wq    = (const float*)d_in[8];
    const float* bq    = (const float*)d_in[9];
    const float* Wa    = (const float*)d_in[10];
    const float* ba    = (const float*)d_in[11];
    const float* Wc    = (const float*)d_in[12];
    const float* bc    = (const float*)d_in[13];
    const float* Wo    = (const float*)d_in[14];
    const float* bo    = (const float*)d_in[15];
    float* out = (float*)d_out;

    float* ws = (float*)d_ws;
    size_t o = 0;
    float* xp      = ws + o; o += (size_t)1024 * 4096;   // 16 MB
    float* h_all   = ws + o; o += (size_t)1024 * 1024;   // 4 MB
    unsigned* rec  = (unsigned*)(ws + o); o += 2 * 8192; // 2 slots x 4096 {h,tag} pairs
    float* rnk     = ws + o; o += NKEY;                  // importance/||key||
    float* qbuf    = ws + o; o += (size_t)ROWS * 256;
    float* qn      = ws + o; o += (size_t)ROWS * 256;
    float* part_v  = ws + o; o += (size_t)ROWS * NS * 3;
    int*   part_i  = (int*)(ws + o); o += (size_t)ROWS * NS * 3;
    int*   top_i   = (int*)(ws + o); o += 4096;
    float* mem_raw = ws + o; o += (size_t)ROWS * 256;
    float* memb    = ws + o; o += (size_t)ROWS * 256;

    // zero records: slot-0 tags = 0 (= step-0 tag) with h = 0 (initial state)
    hipMemsetAsync(rec, 0, 2 * 4096 * 8, stream);

    rownorm<<<NKEY / 4, 256, 0, stream>>>(keys, imp, rnk, nullptr, NKEY);

    // x_proj = x @ W_ih^T + b_ih + b_hh : [1024, 4096]
    sgemm_nt<<<dim3(64, 16), 256, 0, stream>>>(x, ID, W_ih, ID, xp, 4096, ID, b_ih, b_hh, 0);

    // LSTM recurrence (persistent, tagged-record exchange, 64x1024)
    lstm_kernel<<<NWG_LSTM, NTH_LSTM, 0, stream>>>(xp, W_hh, rec, h_all);

    // q = h @ Wq^T + bq : [1024, 256]
    sgemm_nt<<<dim3(4, 16), 256, 0, stream>>>(h_all, HD, Wq, HD, qbuf, MD, HD, bq, nullptr, 0);

    rownorm<<<ROWS / 4, 256, 0, stream>>>(qbuf, nullptr, nullptr, qn, ROWS);

    sim_topk<<<dim3(NS, 16), 256, 0, stream>>>(qn, keys, rnk, part_v, part_i);
    topk_combine<<<ROWS / 256, 256, 0, stream>>>(part_v, part_i, top_i);

    mem_gather<<<ROWS, 64, 0, stream>>>(top_i, values, Wa, ba, mem_raw);

    // mem = mem_raw @ Wc^T + bc
    sgemm_nt<<<dim3(4, 16), 256, 0, stream>>>(mem_raw, MD, Wc, MD, memb, MD, MD, bc, nullptr, 0);

    // out = [h, mem] @ Wo^T + bo  (split K)
    sgemm_nt<<<dim3(8, 16), 256, 0, stream>>>(h_all, HD, Wo, HD + MD, out, OD, HD, bo, nullptr, 0);
    sgemm_nt<<<dim3(8, 16), 256, 0, stream>>>(memb, MD, Wo + HD, HD + MD, out, OD, MD, nullptr, nullptr, 1);
}

// Round 7
// 2493.929 us; speedup vs baseline: 1.5414x; 1.5414x over previous
//
#include <hip/hip_runtime.h>
#include <hip/hip_bf16.h>
#include <cstdint>
#include <cstddef>

// Problem constants
#define BB 4
#define SS 256
#define ID 512
#define HD 1024
#define MD 256
#define NKEY 65536
#define OD 512
#define ROWS 1024          // B*S
#define NS 16              // key-range splits for sim/topk
#define KEYS_PER_NS (NKEY / NS)
#define NWG_LSTM 256
#define NTH_LSTM 256

// ---------------------------------------------------------------------------
// Generic SGEMM: C[M,N] = A[M,K] * Bm[N,K]^T (+bias(+bias2)) or C += ...
// 64x64 tile, 256 threads, 4x4 micro-tile. Grid: (N/64, M/64).
// ---------------------------------------------------------------------------
__global__ __launch_bounds__(256) void sgemm_nt(
    const float* __restrict__ A, int lda,
    const float* __restrict__ Bm, int ldb,
    float* __restrict__ C, int ldc, int K,
    const float* __restrict__ bias, const float* __restrict__ bias2,
    int accum)
{
    __shared__ float As[64][17];
    __shared__ float Bs[64][17];
    const int t = threadIdx.x;
    const int tx = t & 15, ty = t >> 4;
    const int bm = blockIdx.y << 6, bn = blockIdx.x << 6;
    const int lrow = t >> 2, lk4 = (t & 3) << 2;
    float acc[4][4] = {};

    for (int kb = 0; kb < K; kb += 16) {
        const float4 av = *(const float4*)&A[(size_t)(bm + lrow) * lda + kb + lk4];
        const float4 bv = *(const float4*)&Bm[(size_t)(bn + lrow) * ldb + kb + lk4];
        __syncthreads();
        As[lrow][lk4 + 0] = av.x; As[lrow][lk4 + 1] = av.y;
        As[lrow][lk4 + 2] = av.z; As[lrow][lk4 + 3] = av.w;
        Bs[lrow][lk4 + 0] = bv.x; Bs[lrow][lk4 + 1] = bv.y;
        Bs[lrow][lk4 + 2] = bv.z; Bs[lrow][lk4 + 3] = bv.w;
        __syncthreads();
#pragma unroll
        for (int k = 0; k < 16; ++k) {
            const float a0 = As[4 * ty + 0][k], a1 = As[4 * ty + 1][k];
            const float a2 = As[4 * ty + 2][k], a3 = As[4 * ty + 3][k];
            const float b0 = Bs[4 * tx + 0][k], b1 = Bs[4 * tx + 1][k];
            const float b2 = Bs[4 * tx + 2][k], b3 = Bs[4 * tx + 3][k];
            acc[0][0] += a0 * b0; acc[0][1] += a0 * b1; acc[0][2] += a0 * b2; acc[0][3] += a0 * b3;
            acc[1][0] += a1 * b0; acc[1][1] += a1 * b1; acc[1][2] += a1 * b2; acc[1][3] += a1 * b3;
            acc[2][0] += a2 * b0; acc[2][1] += a2 * b1; acc[2][2] += a2 * b2; acc[2][3] += a2 * b3;
            acc[3][0] += a3 * b0; acc[3][1] += a3 * b1; acc[3][2] += a3 * b2; acc[3][3] += a3 * b3;
        }
    }

#pragma unroll
    for (int i = 0; i < 4; ++i) {
        const int row = bm + 4 * ty + i;
        const int col = bn + 4 * tx;
        float4* cp = (float4*)&C[(size_t)row * ldc + col];
        float4 r;
        if (accum) {
            const float4 old = *cp;
            r.x = old.x + acc[i][0]; r.y = old.y + acc[i][1];
            r.z = old.z + acc[i][2]; r.w = old.w + acc[i][3];
        } else {
            float bx = bias[col + 0], by = bias[col + 1], bz = bias[col + 2], bw = bias[col + 3];
            if (bias2) { bx += bias2[col + 0]; by += bias2[col + 1]; bz += bias2[col + 2]; bw += bias2[col + 3]; }
            r.x = acc[i][0] + bx; r.y = acc[i][1] + by;
            r.z = acc[i][2] + bz; r.w = acc[i][3] + bw;
        }
        *cp = r;
    }
}

// ---------------------------------------------------------------------------
// Row L2-normalization helper (256-column rows).
// ---------------------------------------------------------------------------
__global__ void rownorm(const float* __restrict__ X, const float* __restrict__ imp,
                        float* __restrict__ scale_out, float* __restrict__ Xn, int nrows)
{
    const int row = blockIdx.x * 4 + (threadIdx.x >> 6);
    const int lane = threadIdx.x & 63;
    if (row >= nrows) return;
    float4 v = *(const float4*)&X[(size_t)row * 256 + (lane << 2)];
    float ss = v.x * v.x + v.y * v.y + v.z * v.z + v.w * v.w;
#pragma unroll
    for (int o = 1; o < 64; o <<= 1) ss += __shfl_xor(ss, o);
    float sc = 1.f / fmaxf(sqrtf(ss), 1e-12f);
    if (imp) sc *= imp[row];
    if (scale_out && lane == 0) scale_out[row] = sc;
    if (Xn) {
        v.x *= sc; v.y *= sc; v.z *= sc; v.w *= sc;
        *(float4*)&Xn[(size_t)row * 256 + (lane << 2)] = v;
    }
}

// ---------------------------------------------------------------------------
// Persistent LSTM: 256 wgs x 256 threads. Wave w of wg g owns hidden unit
// (4g+w); its 4 W_hh gate rows live in registers. Cross-wg h exchange via
// 4B mantissa-tagged records: rec[slot][b*1024+unit] = bits(h) with the low
// 8 mantissa bits replaced by (step & 0xFF). One coherent dword store gives
// atomic data+readiness visibility; perturbation <= 2^-16 relative (masked
// to zero on consume; full-precision h archived separately). Thread t polls
// 4 dwordx4 (records [i*1024 + 4t .. +3], i=b) -> 262K requests/round chip-
// wide, half of the 8B scheme. De-interleave to LDS [b][unit] unchanged.
// ---------------------------------------------------------------------------
__device__ inline float sigm_f(float x) { return 1.f / (1.f + __expf(-x)); }
__device__ inline float tanh_f(float x) { return 1.f - 2.f / (__expf(2.f * x) + 1.f); }

__global__ __launch_bounds__(256) void lstm_kernel(
    const float* __restrict__ xp, const float* __restrict__ W_hh,
    unsigned* __restrict__ rec, float* __restrict__ h_all)
{
    __shared__ float h_lds[4 * 1024];
    const int t = threadIdx.x;
    const int wave = t >> 6, lane = t & 63;
    const int gt = lane >> 4, ksub = lane & 15;   // gate 0..3 (i,f,g,o), k-sub 0..15
    const int unit = (blockIdx.x << 2) + wave;
    const int wrow = (gt << 10) + unit;           // W_hh row

    float4 w4[16];
#pragma unroll
    for (int j = 0; j < 16; ++j)
        w4[j] = *(const float4*)&W_hh[(size_t)wrow * 1024 + (ksub << 2) + (j << 6)];

    float c[4] = {0.f, 0.f, 0.f, 0.f};           // cell state, replicated per-lane

    // prefetch xp for step 0 (constant data, plain cached loads)
    float xpv[4];
#pragma unroll
    for (int b = 0; b < 4; ++b)
        xpv[b] = xp[(size_t)((b << 8) + 0) * 4096 + wrow];

    for (int s = 0; s < 256; ++s) {
        // ---- poll + load h_s records: 4 x dwordx4 = 16 records of 4B ----
        unsigned* slot = rec + ((size_t)(s & 1) << 12);
        const uint4* p0 = (const uint4*)(slot)          + t;   // b=0, units 4t..4t+3
        const uint4* p1 = (const uint4*)(slot + 1024)   + t;   // b=1
        const uint4* p2 = (const uint4*)(slot + 2048)   + t;   // b=2
        const uint4* p3 = (const uint4*)(slot + 3072)   + t;   // b=3
        uint4 u0, u1, u2, u3;
        const unsigned st = (unsigned)s & 0xFFu;
        while (1) {
            asm volatile(
                "global_load_dwordx4 %0, %4, off sc0 sc1\n\t"
                "global_load_dwordx4 %1, %5, off sc0 sc1\n\t"
                "global_load_dwordx4 %2, %6, off sc0 sc1\n\t"
                "global_load_dwordx4 %3, %7, off sc0 sc1\n\t"
                "s_waitcnt vmcnt(0)"
                : "=&v"(u0), "=&v"(u1), "=&v"(u2), "=&v"(u3)
                : "v"(p0), "v"(p1), "v"(p2), "v"(p3)
                : "memory");
            const unsigned m =
                ((u0.x ^ st) | (u0.y ^ st) | (u0.z ^ st) | (u0.w ^ st) |
                 (u1.x ^ st) | (u1.y ^ st) | (u1.z ^ st) | (u1.w ^ st) |
                 (u2.x ^ st) | (u2.y ^ st) | (u2.z ^ st) | (u2.w ^ st) |
                 (u3.x ^ st) | (u3.y ^ st) | (u3.z ^ st) | (u3.w ^ st)) & 0xFFu;
            if (m == 0u) break;
            __builtin_amdgcn_s_sleep(1);
        }
        // de-interleave (mask tag byte to zero): LDS [b][unit], float4 at 4t
        {
            const unsigned msk = ~0xFFu;
            float4 h0, h1, h2, h3;
            h0.x = __uint_as_float(u0.x & msk); h0.y = __uint_as_float(u0.y & msk);
            h0.z = __uint_as_float(u0.z & msk); h0.w = __uint_as_float(u0.w & msk);
            h1.x = __uint_as_float(u1.x & msk); h1.y = __uint_as_float(u1.y & msk);
            h1.z = __uint_as_float(u1.z & msk); h1.w = __uint_as_float(u1.w & msk);
            h2.x = __uint_as_float(u2.x & msk); h2.y = __uint_as_float(u2.y & msk);
            h2.z = __uint_as_float(u2.z & msk); h2.w = __uint_as_float(u2.w & msk);
            h3.x = __uint_as_float(u3.x & msk); h3.y = __uint_as_float(u3.y & msk);
            h3.z = __uint_as_float(u3.z & msk); h3.w = __uint_as_float(u3.w & msk);
            *(float4*)&h_lds[(t << 2)]        = h0;
            *(float4*)&h_lds[1024 + (t << 2)] = h1;
            *(float4*)&h_lds[2048 + (t << 2)] = h2;
            *(float4*)&h_lds[3072 + (t << 2)] = h3;
        }
        __syncthreads();

        float sum[4];
#pragma unroll
        for (int b = 0; b < 4; ++b) {
            const float* hb = &h_lds[b << 10];
            float ax = 0.f, ay = 0.f, az = 0.f, aw = 0.f;
#pragma unroll
            for (int j = 0; j < 16; ++j) {
                const float4 hv = *(const float4*)&hb[(ksub << 2) + (j << 6)];
                ax += w4[j].x * hv.x; ay += w4[j].y * hv.y;
                az += w4[j].z * hv.z; aw += w4[j].w * hv.w;
            }
            float sm = (ax + ay) + (az + aw);
            sm += __shfl_xor(sm, 1); sm += __shfl_xor(sm, 2);
            sm += __shfl_xor(sm, 4); sm += __shfl_xor(sm, 8);
            sum[b] = sm + xpv[b];                // gate preact, replicated over ksub lanes
        }

#pragma unroll
        for (int b = 0; b < 4; ++b) {
            const float vi = __shfl(sum[b], ksub);
            const float vf = __shfl(sum[b], ksub + 16);
            const float vg = __shfl(sum[b], ksub + 32);
            const float vo = __shfl(sum[b], ksub + 48);
            const float iv = sigm_f(vi), fv = sigm_f(vf);
            const float gv = tanh_f(vg), ov = sigm_f(vo);
            c[b] = fv * c[b] + iv * gv;
            const float hv = ov * tanh_f(c[b]);
            if (lane == b) {
                unsigned* dst = rec + (((size_t)((s + 1) & 1)) << 12) + (b << 10) + unit;
                const unsigned uv = (__float_as_uint(hv) & ~0xFFu) |
                                    ((unsigned)(s + 1) & 0xFFu);
                asm volatile("global_store_dword %0, %1, off sc0 sc1"
                             :: "v"(dst), "v"(uv) : "memory");
                h_all[(size_t)((b << 8) + s) * 1024 + unit] = hv;   // full-precision archive
            }
        }

        if (s == 255) break;
        // prefetch xp for step s+1 (off the critical path, cached)
#pragma unroll
        for (int b = 0; b < 4; ++b)
            xpv[b] = xp[(size_t)((b << 8) + s + 1) * 4096 + wrow];
        // No barrier needed: a thread's step-(s+1) poll succeeds only after ALL
        // waves stored s+1 records, which data-depends on their step-s LDS
        // reads -> safe to overwrite h_lds after poll.
    }
}

// ---------------------------------------------------------------------------
// Fused cosine-sim GEMM + running top-3.
// Grid: (NS, 16). Block 256 (16tx x 16ty), micro 4q x 4k from k-major LDS.
// ---------------------------------------------------------------------------
__global__ __launch_bounds__(256) void sim_topk(
    const float* __restrict__ qn, const float* __restrict__ keys,
    const float* __restrict__ rnk, float* __restrict__ part_v, int* __restrict__ part_i)
{
    __shared__ float Qs[256 * 64];   // k-major: Qs[k*64 + q]
    __shared__ float Ks[256 * 64];   // k-major: Ks[k*64 + key]
    const int t = threadIdx.x;
    const int tx = t & 15, ty = t >> 4;
    const int ns = blockIdx.x, qb = blockIdx.y;
    const int q0 = qb << 6;
    const int rl = t >> 2, c0 = t & 3;

#pragma unroll
    for (int i = 0; i < 16; ++i) {
        const int ch = c0 + (i << 2);
        const float4 v = *(const float4*)&qn[(size_t)(q0 + rl) * 256 + (ch << 2)];
        const int k = ch << 2;
        Qs[(k + 0) * 64 + rl] = v.x; Qs[(k + 1) * 64 + rl] = v.y;
        Qs[(k + 2) * 64 + rl] = v.z; Qs[(k + 3) * 64 + rl] = v.w;
    }

    float rv[4][3]; int ri[4][3];
#pragma unroll
    for (int i = 0; i < 4; ++i) {
        rv[i][0] = rv[i][1] = rv[i][2] = -3e38f;
        ri[i][0] = ri[i][1] = ri[i][2] = 0;
    }

    for (int tile = 0; tile < KEYS_PER_NS / 64; ++tile) {
        const int key0 = ns * KEYS_PER_NS + (tile << 6);
        const float sc = rnk[key0 + rl];
        float4 kreg[16];
#pragma unroll
        for (int i = 0; i < 16; ++i)
            kreg[i] = *(const float4*)&keys[(size_t)(key0 + rl) * 256 + ((c0 + (i << 2)) << 2)];
        __syncthreads();
#pragma unroll
        for (int i = 0; i < 16; ++i) {
            const int k = (c0 + (i << 2)) << 2;
            Ks[(k + 0) * 64 + rl] = kreg[i].x * sc;
            Ks[(k + 1) * 64 + rl] = kreg[i].y * sc;
            Ks[(k + 2) * 64 + rl] = kreg[i].z * sc;
            Ks[(k + 3) * 64 + rl] = kreg[i].w * sc;
        }
        __syncthreads();

        float acc[4][4] = {};
#pragma unroll 4
        for (int k = 0; k < 256; ++k) {
            const float4 a = *(const float4*)&Qs[k * 64 + (ty << 2)];
            const float4 b = *(const float4*)&Ks[k * 64 + (tx << 2)];
            acc[0][0] += a.x * b.x; acc[0][1] += a.x * b.y; acc[0][2] += a.x * b.z; acc[0][3] += a.x * b.w;
            acc[1][0] += a.y * b.x; acc[1][1] += a.y * b.y; acc[1][2] += a.y * b.z; acc[1][3] += a.y * b.w;
            acc[2][0] += a.z * b.x; acc[2][1] += a.z * b.y; acc[2][2] += a.z * b.z; acc[2][3] += a.z * b.w;
            acc[3][0] += a.w * b.x; acc[3][1] += a.w * b.y; acc[3][2] += a.w * b.z; acc[3][3] += a.w * b.w;
        }

#pragma unroll
        for (int i = 0; i < 4; ++i) {
#pragma unroll
            for (int j = 0; j < 4; ++j) {
                const float v = acc[i][j];
                const int gk = key0 + (tx << 2) + j;
                if (v > rv[i][2]) {
                    if (v > rv[i][0]) {
                        rv[i][2] = rv[i][1]; ri[i][2] = ri[i][1];
                        rv[i][1] = rv[i][0]; ri[i][1] = ri[i][0];
                        rv[i][0] = v; ri[i][0] = gk;
                    } else if (v > rv[i][1]) {
                        rv[i][2] = rv[i][1]; ri[i][2] = ri[i][1];
                        rv[i][1] = v; ri[i][1] = gk;
                    } else {
                        rv[i][2] = v; ri[i][2] = gk;
                    }
                }
            }
        }
    }

    __syncthreads();
    float* cv = Qs;               // reuse LDS: [64 q][16 tx][3]
    int* ci = (int*)Ks;
#pragma unroll
    for (int i = 0; i < 4; ++i)
#pragma unroll
        for (int r = 0; r < 3; ++r) {
            cv[(4 * ty + i) * 48 + tx * 3 + r] = rv[i][r];
            ci[(4 * ty + i) * 48 + tx * 3 + r] = ri[i][r];
        }
    __syncthreads();
    if (t < 64) {
        float bv[3] = {-3e38f, -3e38f, -3e38f};
        int bi[3] = {0x7fffffff, 0x7fffffff, 0x7fffffff};
        for (int cc = 0; cc < 48; ++cc) {
            const float v = cv[t * 48 + cc];
            const int id = ci[t * 48 + cc];
            if (v > bv[0] || (v == bv[0] && id < bi[0])) {
                bv[2] = bv[1]; bi[2] = bi[1]; bv[1] = bv[0]; bi[1] = bi[0]; bv[0] = v; bi[0] = id;
            } else if (v > bv[1] || (v == bv[1] && id < bi[1])) {
                bv[2] = bv[1]; bi[2] = bi[1]; bv[1] = v; bi[1] = id;
            } else if (v > bv[2] || (v == bv[2] && id < bi[2])) {
                bv[2] = v; bi[2] = id;
            }
        }
        const size_t base = (size_t)(q0 + t) * (NS * 3) + ns * 3;
        part_v[base + 0] = bv[0]; part_v[base + 1] = bv[1]; part_v[base + 2] = bv[2];
        part_i[base + 0] = bi[0]; part_i[base + 1] = bi[1]; part_i[base + 2] = bi[2];
    }
}

// ---------------------------------------------------------------------------
__global__ void topk_combine(const float* __restrict__ part_v, const int* __restrict__ part_i,
                             int* __restrict__ top_i)
{
    const int q = blockIdx.x * 256 + threadIdx.x;
    if (q >= ROWS) return;
    float bv[3] = {-3e38f, -3e38f, -3e38f};
    int bi[3] = {0x7fffffff, 0x7fffffff, 0x7fffffff};
    for (int cc = 0; cc < NS * 3; ++cc) {
        const float v = part_v[(size_t)q * (NS * 3) + cc];
        const int id = part_i[(size_t)q * (NS * 3) + cc];
        if (v > bv[0] || (v == bv[0] && id < bi[0])) {
            bv[2] = bv[1]; bi[2] = bi[1]; bv[1] = bv[0]; bi[1] = bi[0]; bv[0] = v; bi[0] = id;
        } else if (v > bv[1] || (v == bv[1] && id < bi[1])) {
            bv[2] = bv[1]; bi[2] = bi[1]; bv[1] = v; bi[1] = id;
        } else if (v > bv[2] || (v == bv[2] && id < bi[2])) {
            bv[2] = v; bi[2] = id;
        }
    }
    top_i[q * 3 + 0] = bi[0]; top_i[q * 3 + 1] = bi[1]; top_i[q * 3 + 2] = bi[2];
}

// ---------------------------------------------------------------------------
__global__ void mem_gather(const int* __restrict__ top_i, const float* __restrict__ values,
                           const float* __restrict__ Wa, const float* __restrict__ ba,
                           float* __restrict__ mem_raw)
{
    const int q = blockIdx.x;
    const int lane = threadIdx.x;   // 0..63
    const float4 wa = *(const float4*)&Wa[lane << 2];
    float4 vr[3];
    float lg[3];
#pragma unroll
    for (int r = 0; r < 3; ++r) {
        const int n = top_i[q * 3 + r];
        const float4 v = *(const float4*)&values[(size_t)n * 256 + (lane << 2)];
        vr[r] = v;
        float d = v.x * wa.x + v.y * wa.y + v.z * wa.z + v.w * wa.w;
#pragma unroll
        for (int o = 1; o < 64; o <<= 1) d += __shfl_xor(d, o);
        lg[r] = d + ba[0];
    }
    const float mx = fmaxf(lg[0], fmaxf(lg[1], lg[2]));
    float e0 = __expf(lg[0] - mx), e1 = __expf(lg[1] - mx), e2 = __expf(lg[2] - mx);
    const float inv = 1.f / (e0 + e1 + e2);
    e0 *= inv; e1 *= inv; e2 *= inv;
    float4 m;
    m.x = e0 * vr[0].x + e1 * vr[1].x + e2 * vr[2].x;
    m.y = e0 * vr[0].y + e1 * vr[1].y + e2 * vr[2].y;
    m.z = e0 * vr[0].z + e1 * vr[1].z + e2 * vr[2].z;
    m.w = e0 * vr[0].w + e1 * vr[1].w + e2 * vr[2].w;
    *(float4*)&mem_raw[(size_t)q * 256 + (lane << 2)] = m;
}

// ---------------------------------------------------------------------------
extern "C" void kernel_launch(void* const* d_in, const int* in_sizes, int n_in,
                              void* d_out, int out_size, void* d_ws, size_t ws_size,
                              hipStream_t stream)
{
    (void)in_sizes; (void)n_in; (void)out_size; (void)ws_size;
    const float* x     = (const float*)d_in[0];
    const float* keys  = (const float*)d_in[1];
    const float* values= (const float*)d_in[2];
    const float* imp   = (const float*)d_in[3];
    const float* W_ih  = (const float*)d_in[4];
    const float* W_hh  = (const float*)d_in[5];
    const float* b_ih  = (const float*)d_in[6];
    const float* b_hh  = (const float*)d_in[7];
    const float* Wq    = (const float*)d_in[8];
    const float* bq    = (const float*)d_in[9];
    const float* Wa    = (const float*)d_in[10];
    const float* ba    = (const float*)d_in[11];
    const float* Wc    = (const float*)d_in[12];
    const float* bc    = (const float*)d_in[13];
    const float* Wo    = (const float*)d_in[14];
    const float* bo    = (const float*)d_in[15];
    float* out = (float*)d_out;

    float* ws = (float*)d_ws;
    size_t o = 0;
    float* xp      = ws + o; o += (size_t)1024 * 4096;   // 16 MB
    float* h_all   = ws + o; o += (size_t)1024 * 1024;   // 4 MB
    unsigned* rec  = (unsigned*)(ws + o); o += 2 * 4096; // 2 slots x 4096 4B records
    float* rnk     = ws + o; o += NKEY;                  // importance/||key||
    float* qbuf    = ws + o; o += (size_t)ROWS * 256;
    float* qn      = ws + o; o += (size_t)ROWS * 256;
    float* part_v  = ws + o; o += (size_t)ROWS * NS * 3;
    int*   part_i  = (int*)(ws + o); o += (size_t)ROWS * NS * 3;
    int*   top_i   = (int*)(ws + o); o += 4096;
    float* mem_raw = ws + o; o += (size_t)ROWS * 256;
    float* memb    = ws + o; o += (size_t)ROWS * 256;

    // zero records: slot-0 tag byte = 0 (= step-0 tag) with h = +0.0
    hipMemsetAsync(rec, 0, 2 * 4096 * 4, stream);

    rownorm<<<NKEY / 4, 256, 0, stream>>>(keys, imp, rnk, nullptr, NKEY);

    // x_proj = x @ W_ih^T + b_ih + b_hh : [1024, 4096]
    sgemm_nt<<<dim3(64, 16), 256, 0, stream>>>(x, ID, W_ih, ID, xp, 4096, ID, b_ih, b_hh, 0);

    // LSTM recurrence (persistent, 4B mantissa-tagged record exchange)
    lstm_kernel<<<NWG_LSTM, NTH_LSTM, 0, stream>>>(xp, W_hh, rec, h_all);

    // q = h @ Wq^T + bq : [1024, 256]
    sgemm_nt<<<dim3(4, 16), 256, 0, stream>>>(h_all, HD, Wq, HD, qbuf, MD, HD, bq, nullptr, 0);

    rownorm<<<ROWS / 4, 256, 0, stream>>>(qbuf, nullptr, nullptr, qn, ROWS);

    sim_topk<<<dim3(NS, 16), 256, 0, stream>>>(qn, keys, rnk, part_v, part_i);
    topk_combine<<<ROWS / 256, 256, 0, stream>>>(part_v, part_i, top_i);

    mem_gather<<<ROWS, 64, 0, stream>>>(top_i, values, Wa, ba, mem_raw);

    // mem = mem_raw @ Wc^T + bc
    sgemm_nt<<<dim3(4, 16), 256, 0, stream>>>(mem_raw, MD, Wc, MD, memb, MD, MD, bc, nullptr, 0);

    // out = [h, mem] @ Wo^T + bo  (split K)
    sgemm_nt<<<dim3(8, 16), 256, 0, stream>>>(h_all, HD, Wo, HD + MD, out, OD, HD, bo, nullptr, 0);
    sgemm_nt<<<dim3(8, 16), 256, 0, stream>>>(memb, MD, Wo + HD, HD + MD, out, OD, MD, nullptr, nullptr, 1);
}

// Round 10
// 1854.015 us; speedup vs baseline: 2.0734x; 1.3452x over previous
//
#include <hip/hip_runtime.h>
#include <hip/hip_bf16.h>
#include <cstdint>
#include <cstddef>

// Problem constants
#define BB 4
#define SS 256
#define ID 512
#define HD 1024
#define MD 256
#define NKEY 65536
#define OD 512
#define ROWS 1024          // B*S
#define NS 16              // key-range splits for sim/topk
#define KEYS_PER_NS (NKEY / NS)
#define NWG_LSTM 256
#define NTH_LSTM 256

// ---------------------------------------------------------------------------
// Generic SGEMM: C[M,N] = A[M,K] * Bm[N,K]^T (+bias(+bias2)) or C += ...
// 64x64 tile, 256 threads, 4x4 micro-tile. Grid: (N/64, M/64).
// ---------------------------------------------------------------------------
__global__ __launch_bounds__(256) void sgemm_nt(
    const float* __restrict__ A, int lda,
    const float* __restrict__ Bm, int ldb,
    float* __restrict__ C, int ldc, int K,
    const float* __restrict__ bias, const float* __restrict__ bias2,
    int accum)
{
    __shared__ float As[64][17];
    __shared__ float Bs[64][17];
    const int t = threadIdx.x;
    const int tx = t & 15, ty = t >> 4;
    const int bm = blockIdx.y << 6, bn = blockIdx.x << 6;
    const int lrow = t >> 2, lk4 = (t & 3) << 2;
    float acc[4][4] = {};

    for (int kb = 0; kb < K; kb += 16) {
        const float4 av = *(const float4*)&A[(size_t)(bm + lrow) * lda + kb + lk4];
        const float4 bv = *(const float4*)&Bm[(size_t)(bn + lrow) * ldb + kb + lk4];
        __syncthreads();
        As[lrow][lk4 + 0] = av.x; As[lrow][lk4 + 1] = av.y;
        As[lrow][lk4 + 2] = av.z; As[lrow][lk4 + 3] = av.w;
        Bs[lrow][lk4 + 0] = bv.x; Bs[lrow][lk4 + 1] = bv.y;
        Bs[lrow][lk4 + 2] = bv.z; Bs[lrow][lk4 + 3] = bv.w;
        __syncthreads();
#pragma unroll
        for (int k = 0; k < 16; ++k) {
            const float a0 = As[4 * ty + 0][k], a1 = As[4 * ty + 1][k];
            const float a2 = As[4 * ty + 2][k], a3 = As[4 * ty + 3][k];
            const float b0 = Bs[4 * tx + 0][k], b1 = Bs[4 * tx + 1][k];
            const float b2 = Bs[4 * tx + 2][k], b3 = Bs[4 * tx + 3][k];
            acc[0][0] += a0 * b0; acc[0][1] += a0 * b1; acc[0][2] += a0 * b2; acc[0][3] += a0 * b3;
            acc[1][0] += a1 * b0; acc[1][1] += a1 * b1; acc[1][2] += a1 * b2; acc[1][3] += a1 * b3;
            acc[2][0] += a2 * b0; acc[2][1] += a2 * b1; acc[2][2] += a2 * b2; acc[2][3] += a2 * b3;
            acc[3][0] += a3 * b0; acc[3][1] += a3 * b1; acc[3][2] += a3 * b2; acc[3][3] += a3 * b3;
        }
    }

#pragma unroll
    for (int i = 0; i < 4; ++i) {
        const int row = bm + 4 * ty + i;
        const int col = bn + 4 * tx;
        float4* cp = (float4*)&C[(size_t)row * ldc + col];
        float4 r;
        if (accum) {
            const float4 old = *cp;
            r.x = old.x + acc[i][0]; r.y = old.y + acc[i][1];
            r.z = old.z + acc[i][2]; r.w = old.w + acc[i][3];
        } else {
            float bx = bias[col + 0], by = bias[col + 1], bz = bias[col + 2], bw = bias[col + 3];
            if (bias2) { bx += bias2[col + 0]; by += bias2[col + 1]; bz += bias2[col + 2]; bw += bias2[col + 3]; }
            r.x = acc[i][0] + bx; r.y = acc[i][1] + by;
            r.z = acc[i][2] + bz; r.w = acc[i][3] + bw;
        }
        *cp = r;
    }
}

// ---------------------------------------------------------------------------
// Row L2-normalization helper (256-column rows).
// ---------------------------------------------------------------------------
__global__ void rownorm(const float* __restrict__ X, const float* __restrict__ imp,
                        float* __restrict__ scale_out, float* __restrict__ Xn, int nrows)
{
    const int row = blockIdx.x * 4 + (threadIdx.x >> 6);
    const int lane = threadIdx.x & 63;
    if (row >= nrows) return;
    float4 v = *(const float4*)&X[(size_t)row * 256 + (lane << 2)];
    float ss = v.x * v.x + v.y * v.y + v.z * v.z + v.w * v.w;
#pragma unroll
    for (int o = 1; o < 64; o <<= 1) ss += __shfl_xor(ss, o);
    float sc = 1.f / fmaxf(sqrtf(ss), 1e-12f);
    if (imp) sc *= imp[row];
    if (scale_out && lane == 0) scale_out[row] = sc;
    if (Xn) {
        v.x *= sc; v.y *= sc; v.z *= sc; v.w *= sc;
        *(float4*)&Xn[(size_t)row * 256 + (lane << 2)] = v;
    }
}

// ---------------------------------------------------------------------------
// Persistent LSTM, per-batch sub-step pipeline (round-7 design).
// All hot-loop vmem is inline asm -> the vmcnt FIFO count is exact. Each
// sub-step: {await vmcnt(3) (bare asm, NO tied operands - hipcc can't tie
// vector regs; ordering enforced by sched_barrier(0) right after) -> tag
// check (retry path: blocking vmcnt(0) reload) -> LDS write -> lgkmcnt(0)
// + raw s_barrier (keeps vmcnt pipelined) -> issue next sub-step's poll ->
// compute -> 2 stores + next-step xp load}. Poll for sub-step k is issued
// at k-1 and is the 4th-oldest op at k's await -> vmcnt(3) retires exactly
// it. The xp value used at k was loaded at k-4, drained at k-2's await.
// u0..u3 init 0xFF tag -> first uses take the retry path safely.
// ---------------------------------------------------------------------------
__device__ inline float sigm_f(float x) { return 1.f / (1.f + __expf(-x)); }
__device__ inline float tanh_f(float x) { return 1.f - 2.f / (__expf(2.f * x) + 1.f); }

#define SUBSTEP(B, U, UN, C4, XPC) do {                                           \
    asm volatile("s_waitcnt vmcnt(3)" ::: "memory");                              \
    __builtin_amdgcn_sched_barrier(0);                                            \
    const unsigned* pb_ = rec + (slot << 12) + (B << 10) + (t << 2);              \
    while ((((U.x ^ st) | (U.y ^ st) | (U.z ^ st) | (U.w ^ st)) & 0xFFu) != 0u) { \
        __builtin_amdgcn_s_sleep(1);                                              \
        asm volatile("global_load_dwordx4 %0, %1, off sc0 sc1\n\ts_waitcnt vmcnt(0)" \
                     : "=&v"(U) : "v"(pb_) : "memory");                           \
    }                                                                             \
    {                                                                             \
        float4 hw_;                                                               \
        hw_.x = __uint_as_float(U.x & 0xFFFFFF00u);                               \
        hw_.y = __uint_as_float(U.y & 0xFFFFFF00u);                               \
        hw_.z = __uint_as_float(U.z & 0xFFFFFF00u);                               \
        hw_.w = __uint_as_float(U.w & 0xFFFFFF00u);                               \
        *(float4*)&h_lds[B][t << 2] = hw_;                                        \
    }                                                                             \
    asm volatile("s_waitcnt lgkmcnt(0)" ::: "memory");                            \
    __builtin_amdgcn_sched_barrier(0);                                            \
    __builtin_amdgcn_s_barrier();                                                 \
    {                                                                             \
        const unsigned* pn_ = rec + (((B == 3) ? (slot ^ 1) : slot) << 12)        \
                              + (((B + 1) & 3) << 10) + (t << 2);                 \
        asm volatile("global_load_dwordx4 %0, %1, off sc0 sc1"                    \
                     : "=&v"(UN) : "v"(pn_) : "memory");                          \
    }                                                                             \
    const float* hb_ = &h_lds[B][0];                                              \
    float ax_ = 0.f, ay_ = 0.f, az_ = 0.f, aw_ = 0.f;                             \
    _Pragma("unroll")                                                             \
    for (int j = 0; j < 16; ++j) {                                                \
        const float4 hv_ = *(const float4*)&hb_[(ksub << 2) + (j << 6)];          \
        ax_ += w4[j].x * hv_.x; ay_ += w4[j].y * hv_.y;                           \
        az_ += w4[j].z * hv_.z; aw_ += w4[j].w * hv_.w;                           \
    }                                                                             \
    float sm_ = (ax_ + ay_) + (az_ + aw_);                                        \
    sm_ += __shfl_xor(sm_, 1); sm_ += __shfl_xor(sm_, 2);                         \
    sm_ += __shfl_xor(sm_, 4); sm_ += __shfl_xor(sm_, 8);                         \
    sm_ += XPC;                                                                   \
    const float vi_ = __shfl(sm_, ksub);                                          \
    const float vf_ = __shfl(sm_, ksub + 16);                                     \
    const float vg_ = __shfl(sm_, ksub + 32);                                     \
    const float vo_ = __shfl(sm_, ksub + 48);                                     \
    const float iv_ = sigm_f(vi_), fv_ = sigm_f(vf_);                             \
    const float gv_ = tanh_f(vg_), ov_ = sigm_f(vo_);                             \
    C4 = fv_ * C4 + iv_ * gv_;                                                    \
    const float hvv_ = ov_ * tanh_f(C4);                                          \
    if (lane == 0) {                                                              \
        unsigned* dst_ = rec + ((slot ^ 1) << 12) + (B << 10) + unit;             \
        const unsigned uv_ = (__float_as_uint(hvv_) & 0xFFFFFF00u) |              \
                             ((unsigned)(s + 1) & 0xFFu);                         \
        float* ha_ = &h_all[(size_t)((B << 8) + s) * 1024 + unit];                \
        asm volatile("global_store_dword %0, %1, off sc0 sc1"                     \
                     :: "v"(dst_), "v"(uv_) : "memory");                          \
        asm volatile("global_store_dword %0, %1, off"                             \
                     :: "v"(ha_), "v"(hvv_) : "memory");                          \
    }                                                                             \
    {                                                                             \
        const float* px_ = &xp[(size_t)((B << 8) + sn) * 4096 + wrow];            \
        asm volatile("global_load_dword %0, %1, off"                              \
                     : "=&v"(XPC) : "v"(px_) : "memory");                         \
    }                                                                             \
} while (0)

__global__ __launch_bounds__(256) void lstm_kernel(
    const float* __restrict__ xp, const float* __restrict__ W_hh,
    unsigned* __restrict__ rec, float* __restrict__ h_all)
{
    __shared__ float h_lds[4][1024];
    const int t = threadIdx.x;
    const int wave = t >> 6, lane = t & 63;
    const int gt = lane >> 4, ksub = lane & 15;   // gate 0..3 (i,f,g,o), k-sub 0..15
    const int unit = (blockIdx.x << 2) + wave;
    const int wrow = (gt << 10) + unit;           // W_hh row

    float4 w4[16];
#pragma unroll
    for (int j = 0; j < 16; ++j)
        w4[j] = *(const float4*)&W_hh[(size_t)wrow * 1024 + (ksub << 2) + (j << 6)];

    float c40 = 0.f, c41 = 0.f, c42 = 0.f, c43 = 0.f;   // cell state (per-lane)
    float xpc0 = xp[(size_t)(0 * 256 + 0) * 4096 + wrow];
    float xpc1 = xp[(size_t)(1 * 256 + 0) * 4096 + wrow];
    float xpc2 = xp[(size_t)(2 * 256 + 0) * 4096 + wrow];
    float xpc3 = xp[(size_t)(3 * 256 + 0) * 4096 + wrow];

    uint4 u0 = make_uint4(~0u, ~0u, ~0u, ~0u);    // tag 0xFF -> retry path on
    uint4 u1 = u0, u2 = u0, u3 = u0;              // first use (never a step tag)

    // prologue: issue poll for (s=0,b=0) and drain so the pipeline count is exact
    {
        const unsigned* p00 = rec + (t << 2);
        asm volatile("global_load_dwordx4 %0, %1, off sc0 sc1\n\ts_waitcnt vmcnt(0)"
                     : "=&v"(u0) : "v"(p00) : "memory");
        __builtin_amdgcn_sched_barrier(0);
    }

    for (int s = 0; s < 256; ++s) {
        const int slot = s & 1;
        const unsigned st = (unsigned)s & 0xFFu;
        const int sn = (s < 255) ? s + 1 : 255;   // clamped next-step xp row
        SUBSTEP(0, u0, u1, c40, xpc0);
        SUBSTEP(1, u1, u2, c41, xpc1);
        SUBSTEP(2, u2, u3, c42, xpc2);
        SUBSTEP(3, u3, u0, c43, xpc3);
    }
}

// ---------------------------------------------------------------------------
// Fused cosine-sim GEMM + running top-3.
// Grid: (NS, 16). Block 256 (16tx x 16ty), micro 4q x 4k from k-major LDS.
// ---------------------------------------------------------------------------
__global__ __launch_bounds__(256) void sim_topk(
    const float* __restrict__ qn, const float* __restrict__ keys,
    const float* __restrict__ rnk, float* __restrict__ part_v, int* __restrict__ part_i)
{
    __shared__ float Qs[256 * 64];   // k-major: Qs[k*64 + q]
    __shared__ float Ks[256 * 64];   // k-major: Ks[k*64 + key]
    const int t = threadIdx.x;
    const int tx = t & 15, ty = t >> 4;
    const int ns = blockIdx.x, qb = blockIdx.y;
    const int q0 = qb << 6;
    const int rl = t >> 2, c0 = t & 3;

#pragma unroll
    for (int i = 0; i < 16; ++i) {
        const int ch = c0 + (i << 2);
        const float4 v = *(const float4*)&qn[(size_t)(q0 + rl) * 256 + (ch << 2)];
        const int k = ch << 2;
        Qs[(k + 0) * 64 + rl] = v.x; Qs[(k + 1) * 64 + rl] = v.y;
        Qs[(k + 2) * 64 + rl] = v.z; Qs[(k + 3) * 64 + rl] = v.w;
    }

    float rv[4][3]; int ri[4][3];
#pragma unroll
    for (int i = 0; i < 4; ++i) {
        rv[i][0] = rv[i][1] = rv[i][2] = -3e38f;
        ri[i][0] = ri[i][1] = ri[i][2] = 0;
    }

    for (int tile = 0; tile < KEYS_PER_NS / 64; ++tile) {
        const int key0 = ns * KEYS_PER_NS + (tile << 6);
        const float sc = rnk[key0 + rl];
        float4 kreg[16];
#pragma unroll
        for (int i = 0; i < 16; ++i)
            kreg[i] = *(const float4*)&keys[(size_t)(key0 + rl) * 256 + ((c0 + (i << 2)) << 2)];
        __syncthreads();
#pragma unroll
        for (int i = 0; i < 16; ++i) {
            const int k = (c0 + (i << 2)) << 2;
            Ks[(k + 0) * 64 + rl] = kreg[i].x * sc;
            Ks[(k + 1) * 64 + rl] = kreg[i].y * sc;
            Ks[(k + 2) * 64 + rl] = kreg[i].z * sc;
            Ks[(k + 3) * 64 + rl] = kreg[i].w * sc;
        }
        __syncthreads();

        float acc[4][4] = {};
#pragma unroll 4
        for (int k = 0; k < 256; ++k) {
            const float4 a = *(const float4*)&Qs[k * 64 + (ty << 2)];
            const float4 b = *(const float4*)&Ks[k * 64 + (tx << 2)];
            acc[0][0] += a.x * b.x; acc[0][1] += a.x * b.y; acc[0][2] += a.x * b.z; acc[0][3] += a.x * b.w;
            acc[1][0] += a.y * b.x; acc[1][1] += a.y * b.y; acc[1][2] += a.y * b.z; acc[1][3] += a.y * b.w;
            acc[2][0] += a.z * b.x; acc[2][1] += a.z * b.y; acc[2][2] += a.z * b.z; acc[2][3] += a.z * b.w;
            acc[3][0] += a.w * b.x; acc[3][1] += a.w * b.y; acc[3][2] += a.w * b.z; acc[3][3] += a.w * b.w;
        }

#pragma unroll
        for (int i = 0; i < 4; ++i) {
#pragma unroll
            for (int j = 0; j < 4; ++j) {
                const float v = acc[i][j];
                const int gk = key0 + (tx << 2) + j;
                if (v > rv[i][2]) {
                    if (v > rv[i][0]) {
                        rv[i][2] = rv[i][1]; ri[i][2] = ri[i][1];
                        rv[i][1] = rv[i][0]; ri[i][1] = ri[i][0];
                        rv[i][0] = v; ri[i][0] = gk;
                    } else if (v > rv[i][1]) {
                        rv[i][2] = rv[i][1]; ri[i][2] = ri[i][1];
                        rv[i][1] = v; ri[i][1] = gk;
                    } else {
                        rv[i][2] = v; ri[i][2] = gk;
                    }
                }
            }
        }
    }

    __syncthreads();
    float* cv = Qs;               // reuse LDS: [64 q][16 tx][3]
    int* ci = (int*)Ks;
#pragma unroll
    for (int i = 0; i < 4; ++i)
#pragma unroll
        for (int r = 0; r < 3; ++r) {
            cv[(4 * ty + i) * 48 + tx * 3 + r] = rv[i][r];
            ci[(4 * ty + i) * 48 + tx * 3 + r] = ri[i][r];
        }
    __syncthreads();
    if (t < 64) {
        float bv[3] = {-3e38f, -3e38f, -3e38f};
        int bi[3] = {0x7fffffff, 0x7fffffff, 0x7fffffff};
        for (int cc = 0; cc < 48; ++cc) {
            const float v = cv[t * 48 + cc];
            const int id = ci[t * 48 + cc];
            if (v > bv[0] || (v == bv[0] && id < bi[0])) {
                bv[2] = bv[1]; bi[2] = bi[1]; bv[1] = bv[0]; bi[1] = bi[0]; bv[0] = v; bi[0] = id;
            } else if (v > bv[1] || (v == bv[1] && id < bi[1])) {
                bv[2] = bv[1]; bi[2] = bi[1]; bv[1] = v; bi[1] = id;
            } else if (v > bv[2] || (v == bv[2] && id < bi[2])) {
                bv[2] = v; bi[2] = id;
            }
        }
        const size_t base = (size_t)(q0 + t) * (NS * 3) + ns * 3;
        part_v[base + 0] = bv[0]; part_v[base + 1] = bv[1]; part_v[base + 2] = bv[2];
        part_i[base + 0] = bi[0]; part_i[base + 1] = bi[1]; part_i[base + 2] = bi[2];
    }
}

// ---------------------------------------------------------------------------
__global__ void topk_combine(const float* __restrict__ part_v, const int* __restrict__ part_i,
                             int* __restrict__ top_i)
{
    const int q = blockIdx.x * 256 + threadIdx.x;
    if (q >= ROWS) return;
    float bv[3] = {-3e38f, -3e38f, -3e38f};
    int bi[3] = {0x7fffffff, 0x7fffffff, 0x7fffffff};
    for (int cc = 0; cc < NS * 3; ++cc) {
        const float v = part_v[(size_t)q * (NS * 3) + cc];
        const int id = part_i[(size_t)q * (NS * 3) + cc];
        if (v > bv[0] || (v == bv[0] && id < bi[0])) {
            bv[2] = bv[1]; bi[2] = bi[1]; bv[1] = bv[0]; bi[1] = bi[0]; bv[0] = v; bi[0] = id;
        } else if (v > bv[1] || (v == bv[1] && id < bi[1])) {
            bv[2] = bv[1]; bi[2] = bi[1]; bv[1] = v; bi[1] = id;
        } else if (v > bv[2] || (v == bv[2] && id < bi[2])) {
            bv[2] = v; bi[2] = id;
        }
    }
    top_i[q * 3 + 0] = bi[0]; top_i[q * 3 + 1] = bi[1]; top_i[q * 3 + 2] = bi[2];
}

// ---------------------------------------------------------------------------
__global__ void mem_gather(const int* __restrict__ top_i, const float* __restrict__ values,
                           const float* __restrict__ Wa, const float* __restrict__ ba,
                           float* __restrict__ mem_raw)
{
    const int q = blockIdx.x;
    const int lane = threadIdx.x;   // 0..63
    const float4 wa = *(const float4*)&Wa[lane << 2];
    float4 vr[3];
    float lg[3];
#pragma unroll
    for (int r = 0; r < 3; ++r) {
        const int n = top_i[q * 3 + r];
        const float4 v = *(const float4*)&values[(size_t)n * 256 + (lane << 2)];
        vr[r] = v;
        float d = v.x * wa.x + v.y * wa.y + v.z * wa.z + v.w * wa.w;
#pragma unroll
        for (int o = 1; o < 64; o <<= 1) d += __shfl_xor(d, o);
        lg[r] = d + ba[0];
    }
    const float mx = fmaxf(lg[0], fmaxf(lg[1], lg[2]));
    float e0 = __expf(lg[0] - mx), e1 = __expf(lg[1] - mx), e2 = __expf(lg[2] - mx);
    const float inv = 1.f / (e0 + e1 + e2);
    e0 *= inv; e1 *= inv; e2 *= inv;
    float4 m;
    m.x = e0 * vr[0].x + e1 * vr[1].x + e2 * vr[2].x;
    m.y = e0 * vr[0].y + e1 * vr[1].y + e2 * vr[2].y;
    m.z = e0 * vr[0].z + e1 * vr[1].z + e2 * vr[2].z;
    m.w = e0 * vr[0].w + e1 * vr[1].w + e2 * vr[2].w;
    *(float4*)&mem_raw[(size_t)q * 256 + (lane << 2)] = m;
}

// ---------------------------------------------------------------------------
extern "C" void kernel_launch(void* const* d_in, const int* in_sizes, int n_in,
                              void* d_out, int out_size, void* d_ws, size_t ws_size,
                              hipStream_t stream)
{
    (void)in_sizes; (void)n_in; (void)out_size; (void)ws_size;
    const float* x     = (const float*)d_in[0];
    const float* keys  = (const float*)d_in[1];
    const float* values= (const float*)d_in[2];
    const float* imp   = (const float*)d_in[3];
    const float* W_ih  = (const float*)d_in[4];
    const float* W_hh  = (const float*)d_in[5];
    const float* b_ih  = (const float*)d_in[6];
    const float* b_hh  = (const float*)d_in[7];
    const float* Wq    = (const float*)d_in[8];
    const float* bq    = (const float*)d_in[9];
    const float* Wa    = (const float*)d_in[10];
    const float* ba    = (const float*)d_in[11];
    const float* Wc    = (const float*)d_in[12];
    const float* bc    = (const float*)d_in[13];
    const float* Wo    = (const float*)d_in[14];
    const float* bo    = (const float*)d_in[15];
    float* out = (float*)d_out;

    float* ws = (float*)d_ws;
    size_t o = 0;
    float* xp      = ws + o; o += (size_t)1024 * 4096;   // 16 MB
    float* h_all   = ws + o; o += (size_t)1024 * 1024;   // 4 MB
    unsigned* rec  = (unsigned*)(ws + o); o += 2 * 4096; // 2 slots x 4096 4B records
    float* rnk     = ws + o; o += NKEY;                  // importance/||key||
    float* qbuf    = ws + o; o += (size_t)ROWS * 256;
    float* qn      = ws + o; o += (size_t)ROWS * 256;
    float* part_v  = ws + o; o += (size_t)ROWS * NS * 3;
    int*   part_i  = (int*)(ws + o); o += (size_t)ROWS * NS * 3;
    int*   top_i   = (int*)(ws + o); o += 4096;
    float* mem_raw = ws + o; o += (size_t)ROWS * 256;
    float* memb    = ws + o; o += (size_t)ROWS * 256;

    // zero records: slot-0 tag byte = 0 (= step-0 tag) with h = +0.0
    hipMemsetAsync(rec, 0, 2 * 4096 * 4, stream);

    rownorm<<<NKEY / 4, 256, 0, stream>>>(keys, imp, rnk, nullptr, NKEY);

    // x_proj = x @ W_ih^T + b_ih + b_hh : [1024, 4096]
    sgemm_nt<<<dim3(64, 16), 256, 0, stream>>>(x, ID, W_ih, ID, xp, 4096, ID, b_ih, b_hh, 0);

    // LSTM recurrence (persistent, per-batch sub-step pipelined exchange)
    lstm_kernel<<<NWG_LSTM, NTH_LSTM, 0, stream>>>(xp, W_hh, rec, h_all);

    // q = h @ Wq^T + bq : [1024, 256]
    sgemm_nt<<<dim3(4, 16), 256, 0, stream>>>(h_all, HD, Wq, HD, qbuf, MD, HD, bq, nullptr, 0);

    rownorm<<<ROWS / 4, 256, 0, stream>>>(qbuf, nullptr, nullptr, qn, ROWS);

    sim_topk<<<dim3(NS, 16), 256, 0, stream>>>(qn, keys, rnk, part_v, part_i);
    topk_combine<<<ROWS / 256, 256, 0, stream>>>(part_v, part_i, top_i);

    mem_gather<<<ROWS, 64, 0, stream>>>(top_i, values, Wa, ba, mem_raw);

    // mem = mem_raw @ Wc^T + bc
    sgemm_nt<<<dim3(4, 16), 256, 0, stream>>>(mem_raw, MD, Wc, MD, memb, MD, MD, bc, nullptr, 0);

    // out = [h, mem] @ Wo^T + bo  (split K)
    sgemm_nt<<<dim3(8, 16), 256, 0, stream>>>(h_all, HD, Wo, HD + MD, out, OD, HD, bo, nullptr, 0);
    sgemm_nt<<<dim3(8, 16), 256, 0, stream>>>(memb, MD, Wo + HD, HD + MD, out, OD, MD, nullptr, nullptr, 1);
}